// Round 7
// baseline (104.723 us; speedup 1.0000x reference)
//
#include <hip/hip_runtime.h>
#include <math.h>

typedef unsigned short u16;
typedef __attribute__((ext_vector_type(8))) short bf16x8;
typedef __attribute__((ext_vector_type(4))) float f32x4;

#define BB 2
#define NN 512
#define SCALEF 0.17677669529663687f  // 1/sqrt(16 + 4*4)

__device__ __forceinline__ u16 f2bf(float x) {
  union { float f; unsigned u; } c; c.f = x;
  unsigned r = (c.u + 0x7FFFu + ((c.u >> 16) & 1u)) >> 16;
  return (u16)r;
}
__device__ __forceinline__ float bf2f(u16 h) {
  union { unsigned u; float f; } c; c.u = ((unsigned)h) << 16;
  return c.f;
}

// ============ direct-global MFMA: one wave, 16 rows x NF*16 cols ============
// A[*, lda] rows at arow.., B^T[*, ldb] rows at bcol.., k in [kBeg,kEnd).
// Compensated bf16x3: acc += Ah*Bh + Ah*Bl + Al*Bh. No LDS, no barriers.
template<int NF>
__device__ __forceinline__ void mfma_direct(
    const u16* __restrict__ Ah, const u16* __restrict__ Al, int lda,
    const u16* __restrict__ Bh, const u16* __restrict__ Bl, int ldb,
    int kBeg, int kEnd, int arow, int bcol, f32x4* acc) {
  const int lane = threadIdx.x & 63;
  const int rr = lane & 15, kg = lane >> 4;
  const u16* pah = Ah + (size_t)(arow + rr) * lda + kg * 8;
  const u16* pal = Al + (size_t)(arow + rr) * lda + kg * 8;
  const u16* pbh = Bh + (size_t)(bcol + rr) * ldb + kg * 8;
  const u16* pbl = Bl + (size_t)(bcol + rr) * ldb + kg * 8;
#pragma unroll 2
  for (int k0 = kBeg; k0 < kEnd; k0 += 32) {
    bf16x8 a_h = *(const bf16x8*)(pah + k0);
    bf16x8 a_l = *(const bf16x8*)(pal + k0);
#pragma unroll
    for (int f = 0; f < NF; ++f) {
      bf16x8 b_h = *(const bf16x8*)(pbh + (size_t)f * 16 * ldb + k0);
      bf16x8 b_l = *(const bf16x8*)(pbl + (size_t)f * 16 * ldb + k0);
      acc[f] = __builtin_amdgcn_mfma_f32_16x16x32_bf16(a_h, b_h, acc[f], 0, 0, 0);
      acc[f] = __builtin_amdgcn_mfma_f32_16x16x32_bf16(a_h, b_l, acc[f], 0, 0, 0);
      acc[f] = __builtin_amdgcn_mfma_f32_16x16x32_bf16(a_l, b_h, acc[f], 0, 0, 0);
    }
  }
}

// ---------------- prep: weight transpose+split, hidden split, xyz init ----------------
__global__ __launch_bounds__(256) void prep_kernel(
    const float* __restrict__ hidden, const float* __restrict__ xyz,
    const float* __restrict__ W_qk, const float* __restrict__ W_vs,
    const float* __restrict__ W_pv, const float* __restrict__ W_pqk,
    const float* __restrict__ W_so, const float* __restrict__ W_po,
    const float* __restrict__ W_fp,
    u16* Hhi, u16* Hlo, u16* WINh, u16* WINl,
    u16* WOPh, u16* WOPl, u16* WFPh, u16* WFPl,
    float* out_xyz) {
  const int bid = blockIdx.x, tid = threadIdx.x;
  if (bid < 852) {
    // transpose jobs: src [K][N] -> dst[nOff+n][kOff+k] (hi/lo bf16)
    const float* src; u16 *dh, *dl;
    int Ns, dld, nOff, kOff, tn, lt;
    if (bid < 144)      { src = W_qk;  Ns = 384; dh = WINh; dl = WINl; dld = 384; nOff = 0;   kOff = 0;   tn = 12; lt = bid; }
    else if (bid < 216) { src = W_vs;  Ns = 192; dh = WINh; dl = WINl; dld = 384; nOff = 384; kOff = 0;   tn = 6;  lt = bid - 144; }
    else if (bid < 324) { src = W_pv;  Ns = 288; dh = WINh; dl = WINl; dld = 384; nOff = 576; kOff = 0;   tn = 9;  lt = bid - 216; }
    else if (bid < 384) { src = W_pqk; Ns = 144; dh = WINh; dl = WINl; dld = 384; nOff = 864; kOff = 0;   tn = 5;  lt = bid - 324; }
    else if (bid < 456) { src = W_so;  Ns = 384; dh = WOPh; dl = WOPl; dld = 480; nOff = 0;   kOff = 0;   tn = 12; lt = bid - 384; }
    else if (bid < 564) { src = W_po;  Ns = 384; dh = WOPh; dl = WOPl; dld = 480; nOff = 384; kOff = 192; tn = 12; lt = bid - 456; }
    else                { src = W_fp;  Ns = 384; dh = WFPh; dl = WFPl; dld = 768; nOff = 0;   kOff = 0;   tn = 12; lt = bid - 564; }
    int k0 = (lt / tn) * 32, n0 = (lt % tn) * 32;
    __shared__ float T[32][33];
    int ty = tid >> 5, tx = tid & 31;
    for (int r = ty; r < 32; r += 8) {
      int gn = n0 + tx;
      T[r][tx] = (gn < Ns) ? src[(size_t)(k0 + r) * Ns + gn] : 0.f;
    }
    __syncthreads();
    for (int r = ty; r < 32; r += 8) {
      int gn = n0 + r;
      if (gn < Ns) {
        float v = T[tx][r];
        u16 hi = f2bf(v), lo = f2bf(v - bf2f(hi));
        size_t idx = (size_t)(nOff + gn) * dld + kOff + k0 + tx;
        dh[idx] = hi; dl[idx] = lo;
      }
    }
  } else if (bid < 916) {
    // hidden split: 64 blocks x 1536 float4
    int base = (bid - 852) * 1536;
    for (int u = tid; u < 1536; u += 256) {
      float4 v = ((const float4*)hidden)[base + u];
      u16 h0 = f2bf(v.x), h1 = f2bf(v.y), h2 = f2bf(v.z), h3 = f2bf(v.w);
      u16 l0 = f2bf(v.x - bf2f(h0)), l1 = f2bf(v.y - bf2f(h1));
      u16 l2 = f2bf(v.z - bf2f(h2)), l3 = f2bf(v.w - bf2f(h3));
      ((ushort4*)Hhi)[base + u] = make_ushort4(h0, h1, h2, h3);
      ((ushort4*)Hlo)[base + u] = make_ushort4(l0, l1, l2, l3);
    }
  } else {
    // out_xyz init = xyz : 768 float4
#pragma unroll
    for (int e = 0; e < 3; ++e) {
      int idx = tid + 256 * e;
      ((float4*)out_xyz)[idx] = ((const float4*)xyz)[idx];
    }
  }
}

// ---------------- input projections: barrier-free 1-wave GEMM ----------------
__global__ __launch_bounds__(64) void k_input(
    const u16* __restrict__ Hhi, const u16* __restrict__ Hlo,
    const u16* __restrict__ WINh, const u16* __restrict__ WINl,
    const float* __restrict__ b_qk, const float* __restrict__ b_vs,
    const float* __restrict__ b_pv, const float* __restrict__ b_pqk,
    u16* QKh, u16* QKl, u16* VVh, u16* VVl, float* QPf) {
  f32x4 acc[3] = {};
  int row0 = blockIdx.y * 16, col0 = blockIdx.x * 48;
  mfma_direct<3>(Hhi, Hlo, 384, WINh, WINl, 384, 0, 384, row0, col0, acc);
  int lane = threadIdx.x;
  int rbase = row0 + ((lane >> 4) << 2), cc = lane & 15;
#pragma unroll
  for (int f = 0; f < 3; ++f) {
    int n0 = col0 + f * 16, n = n0 + cc;
    float bias = (n0 < 384) ? b_qk[n]
               : (n0 < 576) ? b_vs[n - 384]
               : (n0 < 864) ? b_pv[n - 576] : b_pqk[n - 864];
#pragma unroll
    for (int r = 0; r < 4; ++r) {
      float v = acc[f][r] + bias;
      int row = rbase + r;
      if (n0 < 384) {
        u16 hi = f2bf(v);
        QKh[(size_t)row * 384 + n] = hi;
        QKl[(size_t)row * 384 + n] = f2bf(v - bf2f(hi));
      } else if (n0 < 864) {
        int c = n - 384;
        u16 hi = f2bf(v);
        VVh[(size_t)row * 480 + c] = hi;
        VVl[(size_t)row * 480 + c] = f2bf(v - bf2f(hi));
      } else {
        QPf[(size_t)row * 144 + (n - 864)] = v;
      }
    }
  }
}

// ---------------- fused logits, symmetric tiles (j0 >= i0) ----------------
// Point term is symmetric (k_points == q_points): compute once, write (i,j)
// and (j,i). Scalar QK is not: MFMA both directions on off-diagonal tiles.
#define PROW 244  // 48*float4(x,y,z,n2) + 48*inv + pad (bank stride 244%32=20: 2-way max)
__global__ __launch_bounds__(256) void k_attn(
    const u16* __restrict__ QKh, const u16* __restrict__ QKl,
    const float* __restrict__ QPf, float* __restrict__ ATTf) {
  __shared__ float Pi[32][PROW];
  __shared__ float Pj[32][PROW];
  __shared__ float Sf[32 * 33];
  const int b = blockIdx.z;
  // decode upper-triangular tile index: 136 tiles, rows of 16,15,...,1
  int t = blockIdx.x, ti_ = 0;
  while (t >= 16 - ti_) { t -= 16 - ti_; ++ti_; }
  const int tj_ = ti_ + t;
  const int i0 = ti_ * 32, j0 = tj_ * 32;
  const bool offdiag = (tj_ != ti_);
  const int tid = threadIdx.x;
  for (int u = tid; u < 3072; u += 256) {
    int side = (u >= 1536) ? 1 : 0;      // 2 sides x 32 rows x 48 hp
    int rem = u - side * 1536;
    int row = rem / 48, hp = rem - row * 48;
    int grow = b * NN + (side ? j0 : i0) + row;
    const float* p = QPf + (size_t)grow * 144 + hp * 3;
    float x = p[0], y = p[1], z = p[2];
    float n2 = x * x + y * y + z * z;
    float inv = __frsqrt_rn(n2 + 1e-12f);
    float* dst = side ? &Pj[row][0] : &Pi[row][0];
    ((float4*)dst)[hp] = make_float4(x, y, z, n2);
    dst[192 + hp] = inv;
  }
  __syncthreads();
  const int tj = tid & 15, ti = tid >> 4;
  float a00 = 0.f, a01 = 0.f, a10 = 0.f, a11 = 0.f;
  {
    const float4* A0 = (const float4*)&Pi[ti][0];
    const float4* A1 = (const float4*)&Pi[ti + 16][0];
    const float4* B0 = (const float4*)&Pj[tj][0];
    const float4* B1 = (const float4*)&Pj[tj + 16][0];
    const float* iA0 = &Pi[ti][192];
    const float* iA1 = &Pi[ti + 16][192];
    const float* iB0 = &Pj[tj][192];
    const float* iB1 = &Pj[tj + 16][192];
#pragma unroll 4
    for (int hp = 0; hp < 48; ++hp) {
      float4 p0 = A0[hp], p1 = A1[hp], q0 = B0[hp], q1 = B1[hp];
      float va0 = iA0[hp], va1 = iA1[hp], vb0 = iB0[hp], vb1 = iB1[hp];
      {
        float dot = p0.x * q0.x + p0.y * q0.y + p0.z * q0.z;
        float d2 = fmaxf(fmaf(-2.f, dot, p0.w + q0.w), 0.f) + 1e-12f;
        a00 += d2 * __frsqrt_rn(d2) + dot * (va0 * vb0);
      }
      {
        float dot = p0.x * q1.x + p0.y * q1.y + p0.z * q1.z;
        float d2 = fmaxf(fmaf(-2.f, dot, p0.w + q1.w), 0.f) + 1e-12f;
        a01 += d2 * __frsqrt_rn(d2) + dot * (va0 * vb1);
      }
      {
        float dot = p1.x * q0.x + p1.y * q0.y + p1.z * q0.z;
        float d2 = fmaxf(fmaf(-2.f, dot, p1.w + q0.w), 0.f) + 1e-12f;
        a10 += d2 * __frsqrt_rn(d2) + dot * (va1 * vb0);
      }
      {
        float dot = p1.x * q1.x + p1.y * q1.y + p1.z * q1.z;
        float d2 = fmaxf(fmaf(-2.f, dot, p1.w + q1.w), 0.f) + 1e-12f;
        a11 += d2 * __frsqrt_rn(d2) + dot * (va1 * vb1);
      }
    }
  }
  Sf[ti * 33 + tj] = a00;
  Sf[ti * 33 + tj + 16] = a01;
  Sf[(ti + 16) * 33 + tj] = a10;
  Sf[(ti + 16) * 33 + tj + 16] = a11;
  // scalar QK via MFMA, direct global frags; both directions if off-diagonal
  f32x4 qij = {}, qji = {};
  const int w = tid >> 6, lane = tid & 63;
  {
    int arow = b * NN + i0 + (w >> 1) * 16;
    int brow = b * NN + j0 + (w & 1) * 16;
    mfma_direct<1>(QKh, QKl, 384, QKh + 192, QKl + 192, 384, 0, 192, arow, brow, &qij);
    if (offdiag) {
      int arow2 = b * NN + j0 + (w >> 1) * 16;
      int brow2 = b * NN + i0 + (w & 1) * 16;
      mfma_direct<1>(QKh, QKl, 384, QKh + 192, QKl + 192, 384, 0, 192, arow2, brow2, &qji);
    }
  }
  __syncthreads();
  const int rl = (w >> 1) * 16 + ((lane >> 4) << 2);
  const int cl = (w & 1) * 16 + (lane & 15);
  float* Cb = ATTf + (size_t)b * NN * NN;
#pragma unroll
  for (int r = 0; r < 4; ++r)
    Cb[(size_t)(i0 + rl + r) * NN + j0 + cl] = qij[r] + Sf[(rl + r) * 33 + cl];
  if (offdiag) {
#pragma unroll
    for (int r = 0; r < 4; ++r)
      Cb[(size_t)(j0 + rl + r) * NN + i0 + cl] = qji[r] + Sf[cl * 33 + rl + r];
  }
}

// ---------------- fused: row softmax (in-place f32 -> bf16 hi/lo) + V transpose ----------------
__global__ __launch_bounds__(256) void k_smvt(
    float* __restrict__ ATTf,
    const u16* __restrict__ VVh, const u16* __restrict__ VVl,
    u16* __restrict__ VTh, u16* __restrict__ VTl) {
  const int bid = blockIdx.x, tid = threadIdx.x;
  if (bid < 1024) {
    float* p = ATTf + (size_t)bid * NN;
    float v0 = p[tid] * SCALEF, v1 = p[tid + 256] * SCALEF;
    __shared__ float red[256];
    red[tid] = fmaxf(v0, v1);
    __syncthreads();
    for (int s = 128; s > 0; s >>= 1) {
      if (tid < s) red[tid] = fmaxf(red[tid], red[tid + s]);
      __syncthreads();
    }
    float m = red[0];
    __syncthreads();
    float e0 = __expf(v0 - m), e1 = __expf(v1 - m);
    red[tid] = e0 + e1;
    __syncthreads();
    for (int s = 128; s > 0; s >>= 1) {
      if (tid < s) red[tid] += red[tid + s];
      __syncthreads();
    }
    float inv = 1.0f / red[0];
    float w0 = e0 * inv, w1 = e1 * inv;
    u16 h0 = f2bf(w0), h1 = f2bf(w1);
    u16* q = (u16*)p;
    q[tid] = h0;
    q[tid + 256] = h1;
    q[512 + tid] = f2bf(w0 - bf2f(h0));
    q[512 + tid + 256] = f2bf(w1 - bf2f(h1));
  } else {
    int t = bid - 1024;                  // 480 tiles = 15 x 16 x 2
    int b = t / 240, rem = t - b * 240;
    int bx = rem % 15, by = rem / 15;
    __shared__ u16 Th[32][34], Tl[32][34];
    int ty = tid >> 5, tx = tid & 31;
    for (int r = ty; r < 32; r += 8) {
      size_t src = (size_t)(b * NN + by * 32 + r) * 480 + bx * 32 + tx;
      Th[r][tx] = VVh[src];
      Tl[r][tx] = VVl[src];
    }
    __syncthreads();
    for (int r = ty; r < 32; r += 8) {
      size_t dst = (size_t)b * 480 * NN + (size_t)(bx * 32 + r) * NN + by * 32 + tx;
      VTh[dst] = Th[tx][r];
      VTl[dst] = Tl[tx][r];
    }
  }
}

// ---------------- PV: barrier-free NT GEMM, A = P (stride-1024 hi/lo), B = VT ----------------
__global__ __launch_bounds__(64) void k_pv(
    const u16* __restrict__ Pb,
    const u16* __restrict__ VTh, const u16* __restrict__ VTl,
    u16* SRh, u16* SRl) {
  f32x4 acc[3] = {};
  const int b = blockIdx.z;
  const int row0 = blockIdx.y * 16, col0 = blockIdx.x * 48;
  const u16* P = Pb + (size_t)b * NN * 1024;
  mfma_direct<3>(P, P + 512, 1024,
                 VTh + (size_t)b * 480 * NN, VTl + (size_t)b * 480 * NN, NN,
                 0, NN, row0, col0, acc);
  const int lane = threadIdx.x;
  const int rbase = row0 + ((lane >> 4) << 2), cc = lane & 15;
  u16* oh = SRh + (size_t)b * NN * 480;
  u16* ol = SRl + (size_t)b * NN * 480;
#pragma unroll
  for (int f = 0; f < 3; ++f) {
    int n = col0 + f * 16 + cc;
#pragma unroll
    for (int r = 0; r < 4; ++r) {
      float v = acc[f][r];
      u16 hi = f2bf(v);
      oh[(size_t)(rbase + r) * 480 + n] = hi;
      ol[(size_t)(rbase + r) * 480 + n] = f2bf(v - bf2f(hi));
    }
  }
}

// ---------------- output projections (live-K only) + fused delta_xyz ----------------
__global__ __launch_bounds__(64) void k_outproj(
    const u16* __restrict__ SRh, const u16* __restrict__ SRl,
    const u16* __restrict__ WOPh, const u16* __restrict__ WOPl,
    const float* __restrict__ b_so, const float* __restrict__ b_po,
    u16* PRh, u16* PRl, float* __restrict__ out_xyz) {
  f32x4 acc[3] = {};
  const int t = blockIdx.x;
  const int row0 = blockIdx.y * 16, col0 = t * 48;
  const int kBeg = (t < 8) ? 0 : 192, kEnd = (t < 8) ? 192 : 480;
  mfma_direct<3>(SRh, SRl, 480, WOPh, WOPl, 480, kBeg, kEnd, row0, col0, acc);
  __shared__ float D[16][49];
  const int lane = threadIdx.x;
  const int rb = (lane >> 4) << 2, cc = lane & 15;
#pragma unroll
  for (int f = 0; f < 3; ++f) {
    int n = col0 + f * 16 + cc;
    float bias = (n < 384) ? b_so[n] : b_po[n - 384];
#pragma unroll
    for (int r = 0; r < 4; ++r) {
      float v = acc[f][r] + bias;
      u16 hi = f2bf(v);
      PRh[(size_t)(row0 + rb + r) * 768 + n] = hi;
      PRl[(size_t)(row0 + rb + r) * 768 + n] = f2bf(v - bf2f(hi));
      if (t >= 8) D[rb + r][f * 16 + cc] = v;
    }
  }
  if (t >= 8) {
    __syncthreads();
    if (lane < 16) {
      float sx = 0.f, sy = 0.f, sz = 0.f;
#pragma unroll
      for (int p = 0; p < 16; ++p) {
        sx += D[lane][3 * p];
        sy += D[lane][3 * p + 1];
        sz += D[lane][3 * p + 2];
      }
      int token = row0 + lane;
      atomicAdd(out_xyz + (size_t)token * 3 + 0, sx * (1.0f / 128.f));
      atomicAdd(out_xyz + (size_t)token * 3 + 1, sy * (1.0f / 128.f));
      atomicAdd(out_xyz + (size_t)token * 3 + 2, sz * (1.0f / 128.f));
    }
  }
}

// ---------------- final: out = PROJ @ WFP^T + b_fp; 2 waves split K, LDS combine ----------------
__global__ __launch_bounds__(128) void k_final(
    const u16* __restrict__ PRh, const u16* __restrict__ PRl,
    const u16* __restrict__ WFPh, const u16* __restrict__ WFPl,
    const float* __restrict__ b_fp, float* __restrict__ out_res) {
  f32x4 acc[3] = {};
  const int row0 = blockIdx.y * 16, col0 = blockIdx.x * 48;
  const int w = threadIdx.x >> 6;
  const int kBeg = w * 384;
  mfma_direct<3>(PRh, PRl, 768, WFPh, WFPl, 768, kBeg, kBeg + 384, row0, col0, acc);
  __shared__ float S[16][52];
  const int lane = threadIdx.x & 63;
  const int rb = (lane >> 4) << 2, cc = lane & 15;
  if (w == 1) {
#pragma unroll
    for (int f = 0; f < 3; ++f)
#pragma unroll
      for (int r = 0; r < 4; ++r)
        S[rb + r][f * 16 + cc] = acc[f][r];
  }
  __syncthreads();
  if (w == 0) {
#pragma unroll
    for (int f = 0; f < 3; ++f) {
      int n = col0 + f * 16 + cc;
#pragma unroll
      for (int r = 0; r < 4; ++r)
        out_res[(size_t)(row0 + rb + r) * 384 + n] =
            acc[f][r] + S[rb + r][f * 16 + cc] + b_fp[n];
    }
  }
}

extern "C" void kernel_launch(void* const* d_in, const int* in_sizes, int n_in,
                              void* d_out, int out_size, void* d_ws, size_t ws_size,
                              hipStream_t stream) {
  const float* hidden = (const float*)d_in[0];
  const float* xyz   = (const float*)d_in[1];
  const float* W_qk  = (const float*)d_in[2];
  const float* b_qk  = (const float*)d_in[3];
  const float* W_vs  = (const float*)d_in[4];
  const float* b_vs  = (const float*)d_in[5];
  const float* W_so  = (const float*)d_in[6];
  const float* b_so  = (const float*)d_in[7];
  const float* W_pqk = (const float*)d_in[8];
  const float* b_pqk = (const float*)d_in[9];
  const float* W_pv  = (const float*)d_in[10];
  const float* b_pv  = (const float*)d_in[11];
  const float* W_po  = (const float*)d_in[12];
  const float* b_po  = (const float*)d_in[13];
  const float* W_fp  = (const float*)d_in[14];
  const float* b_fp  = (const float*)d_in[15];

  float* out_res = (float*)d_out;                  // [B,N,384]
  float* out_xyz = out_res + (size_t)BB * NN * 384;

  u16* Hhi  = (u16*)d_ws;                 // 1024*384
  u16* Hlo  = Hhi  + 393216;
  u16* WINh = Hlo  + 393216;              // 1008*384
  u16* WINl = WINh + 387072;
  u16* WOPh = WINl + 387072;              // 768*480
  u16* WOPl = WOPh + 368640;
  u16* WFPh = WOPl + 368640;              // 384*768
  u16* WFPl = WFPh + 294912;
  u16* QKh  = WFPl + 294912;              // 1024*384
  u16* QKl  = QKh  + 393216;
  u16* VVh  = QKl  + 393216;              // 1024*480
  u16* VVl  = VVh  + 491520;
  u16* SRh  = VVl  + 491520;              // 1024*480
  u16* SRl  = SRh  + 491520;
  u16* PRh  = SRl  + 491520;              // 1024*768
  u16* PRl  = PRh  + 786432;
  float* QPf  = (float*)(PRl + 786432);   // 1024*144 f32
  float* ATTf = QPf + 147456;             // 2*512*512 f32 (becomes P hi/lo u16 after k_smvt)
  // VT overlays Hhi/Hlo/WINh (dead after k_input): 2*480*512 u16 x2
  u16* VTh  = Hhi;
  u16* VTl  = Hhi + 491520;

  prep_kernel<<<917, 256, 0, stream>>>(hidden, xyz, W_qk, W_vs, W_pv, W_pqk,
                                       W_so, W_po, W_fp,
                                       Hhi, Hlo, WINh, WINl, WOPh, WOPl, WFPh, WFPl,
                                       out_xyz);
  k_input<<<dim3(21, 64), 64, 0, stream>>>(Hhi, Hlo, WINh, WINl,
                                           b_qk, b_vs, b_pv, b_pqk,
                                           QKh, QKl, VVh, VVl, QPf);
  k_attn<<<dim3(136, 1, 2), 256, 0, stream>>>(QKh, QKl, QPf, ATTf);
  k_smvt<<<1504, 256, 0, stream>>>(ATTf, VVh, VVl, VTh, VTl);
  k_pv<<<dim3(10, 32, 2), 64, 0, stream>>>((const u16*)ATTf, VTh, VTl, SRh, SRl);
  k_outproj<<<dim3(16, 64), 64, 0, stream>>>(SRh, SRl, WOPh, WOPl, b_so, b_po,
                                             PRh, PRl, out_xyz);
  k_final<<<dim3(8, 64), 128, 0, stream>>>(PRh, PRl, WFPh, WFPl, b_fp, out_res);
}

// Round 8
// 98.803 us; speedup vs baseline: 1.0599x; 1.0599x over previous
//
#include <hip/hip_runtime.h>
#include <math.h>

typedef unsigned short u16;
typedef __attribute__((ext_vector_type(8))) short bf16x8;
typedef __attribute__((ext_vector_type(4))) float f32x4;

#define BB 2
#define NN 512
#define SCALEF 0.17677669529663687f  // 1/sqrt(16 + 4*4)

__device__ __forceinline__ u16 f2bf(float x) {
  union { float f; unsigned u; } c; c.f = x;
  unsigned r = (c.u + 0x7FFFu + ((c.u >> 16) & 1u)) >> 16;
  return (u16)r;
}
__device__ __forceinline__ float bf2f(u16 h) {
  union { unsigned u; float f; } c; c.u = ((unsigned)h) << 16;
  return c.f;
}

// ====== direct-global MFMA tile: one wave, MR*16 rows x NF*16 cols ======
// A[*, lda] rows at arow.., B^T[*, ldb] rows at bcol.., k in [kBeg,kEnd).
// Compensated bf16x3: acc += Ah*Bh + Ah*Bl + Al*Bh. No LDS, no barriers.
template<int MR, int NF>
__device__ __forceinline__ void mfma_tile(
    const u16* __restrict__ Ah, const u16* __restrict__ Al, int lda,
    const u16* __restrict__ Bh, const u16* __restrict__ Bl, int ldb,
    int kBeg, int kEnd, int arow, int bcol, f32x4 (&acc)[MR][NF]) {
  const int lane = threadIdx.x & 63;
  const int rr = lane & 15, kg = lane >> 4;
  const u16* pah = Ah + (size_t)(arow + rr) * lda + kg * 8;
  const u16* pal = Al + (size_t)(arow + rr) * lda + kg * 8;
  const u16* pbh = Bh + (size_t)(bcol + rr) * ldb + kg * 8;
  const u16* pbl = Bl + (size_t)(bcol + rr) * ldb + kg * 8;
#pragma unroll 2
  for (int k0 = kBeg; k0 < kEnd; k0 += 32) {
    bf16x8 a_h[MR], a_l[MR], b_h[NF], b_l[NF];
#pragma unroll
    for (int m = 0; m < MR; ++m) {
      a_h[m] = *(const bf16x8*)(pah + (size_t)m * 16 * lda + k0);
      a_l[m] = *(const bf16x8*)(pal + (size_t)m * 16 * lda + k0);
    }
#pragma unroll
    for (int f = 0; f < NF; ++f) {
      b_h[f] = *(const bf16x8*)(pbh + (size_t)f * 16 * ldb + k0);
      b_l[f] = *(const bf16x8*)(pbl + (size_t)f * 16 * ldb + k0);
    }
#pragma unroll
    for (int m = 0; m < MR; ++m)
#pragma unroll
      for (int f = 0; f < NF; ++f) {
        acc[m][f] = __builtin_amdgcn_mfma_f32_16x16x32_bf16(a_h[m], b_h[f], acc[m][f], 0, 0, 0);
        acc[m][f] = __builtin_amdgcn_mfma_f32_16x16x32_bf16(a_h[m], b_l[f], acc[m][f], 0, 0, 0);
        acc[m][f] = __builtin_amdgcn_mfma_f32_16x16x32_bf16(a_l[m], b_h[f], acc[m][f], 0, 0, 0);
      }
  }
}

// ---------------- prep: weight transpose+split, hidden split, xyz init ----------------
__global__ __launch_bounds__(256) void prep_kernel(
    const float* __restrict__ hidden, const float* __restrict__ xyz,
    const float* __restrict__ W_qk, const float* __restrict__ W_vs,
    const float* __restrict__ W_pv, const float* __restrict__ W_pqk,
    const float* __restrict__ W_so, const float* __restrict__ W_po,
    const float* __restrict__ W_fp,
    u16* Hhi, u16* Hlo, u16* WINh, u16* WINl,
    u16* WOPh, u16* WOPl, u16* WFPh, u16* WFPl,
    float* out_xyz) {
  const int bid = blockIdx.x, tid = threadIdx.x;
  if (bid < 852) {
    // transpose jobs: src [K][N] -> dst[nOff+n][kOff+k] (hi/lo bf16)
    const float* src; u16 *dh, *dl;
    int Ns, dld, nOff, kOff, tn, lt;
    if (bid < 144)      { src = W_qk;  Ns = 384; dh = WINh; dl = WINl; dld = 384; nOff = 0;   kOff = 0;   tn = 12; lt = bid; }
    else if (bid < 216) { src = W_vs;  Ns = 192; dh = WINh; dl = WINl; dld = 384; nOff = 384; kOff = 0;   tn = 6;  lt = bid - 144; }
    else if (bid < 324) { src = W_pv;  Ns = 288; dh = WINh; dl = WINl; dld = 384; nOff = 576; kOff = 0;   tn = 9;  lt = bid - 216; }
    else if (bid < 384) { src = W_pqk; Ns = 144; dh = WINh; dl = WINl; dld = 384; nOff = 864; kOff = 0;   tn = 5;  lt = bid - 324; }
    else if (bid < 456) { src = W_so;  Ns = 384; dh = WOPh; dl = WOPl; dld = 480; nOff = 0;   kOff = 0;   tn = 12; lt = bid - 384; }
    else if (bid < 564) { src = W_po;  Ns = 384; dh = WOPh; dl = WOPl; dld = 480; nOff = 384; kOff = 192; tn = 12; lt = bid - 456; }
    else                { src = W_fp;  Ns = 384; dh = WFPh; dl = WFPl; dld = 768; nOff = 0;   kOff = 0;   tn = 12; lt = bid - 564; }
    int k0 = (lt / tn) * 32, n0 = (lt % tn) * 32;
    __shared__ float T[32][33];
    int ty = tid >> 5, tx = tid & 31;
    for (int r = ty; r < 32; r += 8) {
      int gn = n0 + tx;
      T[r][tx] = (gn < Ns) ? src[(size_t)(k0 + r) * Ns + gn] : 0.f;
    }
    __syncthreads();
    for (int r = ty; r < 32; r += 8) {
      int gn = n0 + r;
      if (gn < Ns) {
        float v = T[tx][r];
        u16 hi = f2bf(v), lo = f2bf(v - bf2f(hi));
        size_t idx = (size_t)(nOff + gn) * dld + kOff + k0 + tx;
        dh[idx] = hi; dl[idx] = lo;
      }
    }
  } else if (bid < 916) {
    // hidden split: 64 blocks x 1536 float4
    int base = (bid - 852) * 1536;
    for (int u = tid; u < 1536; u += 256) {
      float4 v = ((const float4*)hidden)[base + u];
      u16 h0 = f2bf(v.x), h1 = f2bf(v.y), h2 = f2bf(v.z), h3 = f2bf(v.w);
      u16 l0 = f2bf(v.x - bf2f(h0)), l1 = f2bf(v.y - bf2f(h1));
      u16 l2 = f2bf(v.z - bf2f(h2)), l3 = f2bf(v.w - bf2f(h3));
      ((ushort4*)Hhi)[base + u] = make_ushort4(h0, h1, h2, h3);
      ((ushort4*)Hlo)[base + u] = make_ushort4(l0, l1, l2, l3);
    }
  } else {
    // out_xyz init = xyz : 768 float4
#pragma unroll
    for (int e = 0; e < 3; ++e) {
      int idx = tid + 256 * e;
      ((float4*)out_xyz)[idx] = ((const float4*)xyz)[idx];
    }
  }
}

// ---------------- input projections: barrier-free 1-wave GEMM (32x48/wave) ----------------
__global__ __launch_bounds__(64) void k_input(
    const u16* __restrict__ Hhi, const u16* __restrict__ Hlo,
    const u16* __restrict__ WINh, const u16* __restrict__ WINl,
    const float* __restrict__ b_qk, const float* __restrict__ b_vs,
    const float* __restrict__ b_pv, const float* __restrict__ b_pqk,
    u16* QKh, u16* QKl, u16* VVh, u16* VVl, float* QPf) {
  f32x4 acc[2][3] = {};
  int row0 = blockIdx.y * 32, col0 = blockIdx.x * 48;
  mfma_tile<2, 3>(Hhi, Hlo, 384, WINh, WINl, 384, 0, 384, row0, col0, acc);
  int lane = threadIdx.x;
  int rb = (lane >> 4) << 2, cc = lane & 15;
#pragma unroll
  for (int f = 0; f < 3; ++f) {
    int n0 = col0 + f * 16, n = n0 + cc;
    float bias = (n0 < 384) ? b_qk[n]
               : (n0 < 576) ? b_vs[n - 384]
               : (n0 < 864) ? b_pv[n - 576] : b_pqk[n - 864];
#pragma unroll
    for (int m = 0; m < 2; ++m)
#pragma unroll
      for (int r = 0; r < 4; ++r) {
        float v = acc[m][f][r] + bias;
        int row = row0 + m * 16 + rb + r;
        if (n0 < 384) {
          u16 hi = f2bf(v);
          QKh[(size_t)row * 384 + n] = hi;
          QKl[(size_t)row * 384 + n] = f2bf(v - bf2f(hi));
        } else if (n0 < 864) {
          int c = n - 384;
          u16 hi = f2bf(v);
          VVh[(size_t)row * 480 + c] = hi;
          VVl[(size_t)row * 480 + c] = f2bf(v - bf2f(hi));
        } else {
          QPf[(size_t)row * 144 + (n - 864)] = v;
        }
      }
  }
}

// ---------------- fused logits, symmetric tiles (j0 >= i0) ----------------
#define PROW 244  // 48*float4(x,y,z,n2) + 48*inv + pad (bank stride 244%32=20: 2-way max)
__global__ __launch_bounds__(256) void k_attn(
    const u16* __restrict__ QKh, const u16* __restrict__ QKl,
    const float* __restrict__ QPf, float* __restrict__ ATTf) {
  __shared__ float Pi[32][PROW];
  __shared__ float Pj[32][PROW];
  __shared__ float Sf[32 * 33];
  const int b = blockIdx.z;
  int t = blockIdx.x, ti_ = 0;
  while (t >= 16 - ti_) { t -= 16 - ti_; ++ti_; }
  const int tj_ = ti_ + t;
  const int i0 = ti_ * 32, j0 = tj_ * 32;
  const bool offdiag = (tj_ != ti_);
  const int tid = threadIdx.x;
  for (int u = tid; u < 3072; u += 256) {
    int side = (u >= 1536) ? 1 : 0;
    int rem = u - side * 1536;
    int row = rem / 48, hp = rem - row * 48;
    int grow = b * NN + (side ? j0 : i0) + row;
    const float* p = QPf + (size_t)grow * 144 + hp * 3;
    float x = p[0], y = p[1], z = p[2];
    float n2 = x * x + y * y + z * z;
    float inv = __frsqrt_rn(n2 + 1e-12f);
    float* dst = side ? &Pj[row][0] : &Pi[row][0];
    ((float4*)dst)[hp] = make_float4(x, y, z, n2);
    dst[192 + hp] = inv;
  }
  __syncthreads();
  const int tj = tid & 15, ti = tid >> 4;
  float a00 = 0.f, a01 = 0.f, a10 = 0.f, a11 = 0.f;
  {
    const float4* A0 = (const float4*)&Pi[ti][0];
    const float4* A1 = (const float4*)&Pi[ti + 16][0];
    const float4* B0 = (const float4*)&Pj[tj][0];
    const float4* B1 = (const float4*)&Pj[tj + 16][0];
    const float* iA0 = &Pi[ti][192];
    const float* iA1 = &Pi[ti + 16][192];
    const float* iB0 = &Pj[tj][192];
    const float* iB1 = &Pj[tj + 16][192];
#pragma unroll 4
    for (int hp = 0; hp < 48; ++hp) {
      float4 p0 = A0[hp], p1 = A1[hp], q0 = B0[hp], q1 = B1[hp];
      float va0 = iA0[hp], va1 = iA1[hp], vb0 = iB0[hp], vb1 = iB1[hp];
      {
        float dot = p0.x * q0.x + p0.y * q0.y + p0.z * q0.z;
        float d2 = fmaxf(fmaf(-2.f, dot, p0.w + q0.w), 0.f) + 1e-12f;
        a00 += d2 * __frsqrt_rn(d2) + dot * (va0 * vb0);
      }
      {
        float dot = p0.x * q1.x + p0.y * q1.y + p0.z * q1.z;
        float d2 = fmaxf(fmaf(-2.f, dot, p0.w + q1.w), 0.f) + 1e-12f;
        a01 += d2 * __frsqrt_rn(d2) + dot * (va0 * vb1);
      }
      {
        float dot = p1.x * q0.x + p1.y * q0.y + p1.z * q0.z;
        float d2 = fmaxf(fmaf(-2.f, dot, p1.w + q0.w), 0.f) + 1e-12f;
        a10 += d2 * __frsqrt_rn(d2) + dot * (va1 * vb0);
      }
      {
        float dot = p1.x * q1.x + p1.y * q1.y + p1.z * q1.z;
        float d2 = fmaxf(fmaf(-2.f, dot, p1.w + q1.w), 0.f) + 1e-12f;
        a11 += d2 * __frsqrt_rn(d2) + dot * (va1 * vb1);
      }
    }
  }
  Sf[ti * 33 + tj] = a00;
  Sf[ti * 33 + tj + 16] = a01;
  Sf[(ti + 16) * 33 + tj] = a10;
  Sf[(ti + 16) * 33 + tj + 16] = a11;
  // scalar QK via MFMA, direct global frags; both directions if off-diagonal
  f32x4 qij[1][1] = {}, qji[1][1] = {};
  const int w = tid >> 6, lane = tid & 63;
  {
    int arow = b * NN + i0 + (w >> 1) * 16;
    int brow = b * NN + j0 + (w & 1) * 16;
    mfma_tile<1, 1>(QKh, QKl, 384, QKh + 192, QKl + 192, 384, 0, 192, arow, brow, qij);
    if (offdiag) {
      int arow2 = b * NN + j0 + (w >> 1) * 16;
      int brow2 = b * NN + i0 + (w & 1) * 16;
      mfma_tile<1, 1>(QKh, QKl, 384, QKh + 192, QKl + 192, 384, 0, 192, arow2, brow2, qji);
    }
  }
  __syncthreads();
  const int rl = (w >> 1) * 16 + ((lane >> 4) << 2);
  const int cl = (w & 1) * 16 + (lane & 15);
  float* Cb = ATTf + (size_t)b * NN * NN;
#pragma unroll
  for (int r = 0; r < 4; ++r)
    Cb[(size_t)(i0 + rl + r) * NN + j0 + cl] = qij[0][0][r] + Sf[(rl + r) * 33 + cl];
  if (offdiag) {
#pragma unroll
    for (int r = 0; r < 4; ++r)
      Cb[(size_t)(j0 + rl + r) * NN + i0 + cl] = qji[0][0][r] + Sf[cl * 33 + rl + r];
  }
}

// ---------------- fused: row softmax (in-place f32 -> bf16 hi/lo) + V transpose ----------------
__global__ __launch_bounds__(256) void k_smvt(
    float* __restrict__ ATTf,
    const u16* __restrict__ VVh, const u16* __restrict__ VVl,
    u16* __restrict__ VTh, u16* __restrict__ VTl) {
  const int bid = blockIdx.x, tid = threadIdx.x;
  if (bid < 1024) {
    float* p = ATTf + (size_t)bid * NN;
    float v0 = p[tid] * SCALEF, v1 = p[tid + 256] * SCALEF;
    __shared__ float red[256];
    red[tid] = fmaxf(v0, v1);
    __syncthreads();
    for (int s = 128; s > 0; s >>= 1) {
      if (tid < s) red[tid] = fmaxf(red[tid], red[tid + s]);
      __syncthreads();
    }
    float m = red[0];
    __syncthreads();
    float e0 = __expf(v0 - m), e1 = __expf(v1 - m);
    red[tid] = e0 + e1;
    __syncthreads();
    for (int s = 128; s > 0; s >>= 1) {
      if (tid < s) red[tid] += red[tid + s];
      __syncthreads();
    }
    float inv = 1.0f / red[0];
    float w0 = e0 * inv, w1 = e1 * inv;
    u16 h0 = f2bf(w0), h1 = f2bf(w1);
    u16* q = (u16*)p;
    q[tid] = h0;
    q[tid + 256] = h1;
    q[512 + tid] = f2bf(w0 - bf2f(h0));
    q[512 + tid + 256] = f2bf(w1 - bf2f(h1));
  } else {
    int t = bid - 1024;                  // 480 tiles = 15 x 16 x 2
    int b = t / 240, rem = t - b * 240;
    int bx = rem % 15, by = rem / 15;
    __shared__ u16 Th[32][34], Tl[32][34];
    int ty = tid >> 5, tx = tid & 31;
    for (int r = ty; r < 32; r += 8) {
      size_t src = (size_t)(b * NN + by * 32 + r) * 480 + bx * 32 + tx;
      Th[r][tx] = VVh[src];
      Tl[r][tx] = VVl[src];
    }
    __syncthreads();
    for (int r = ty; r < 32; r += 8) {
      size_t dst = (size_t)b * 480 * NN + (size_t)(bx * 32 + r) * NN + by * 32 + tx;
      VTh[dst] = Th[tx][r];
      VTl[dst] = Tl[tx][r];
    }
  }
}

// ---------------- PV: barrier-free NT GEMM (32x48/wave), A = P hi/lo, B = VT ----------------
__global__ __launch_bounds__(64) void k_pv(
    const u16* __restrict__ Pb,
    const u16* __restrict__ VTh, const u16* __restrict__ VTl,
    u16* SRh, u16* SRl) {
  f32x4 acc[2][3] = {};
  const int b = blockIdx.z;
  const int row0 = blockIdx.y * 32, col0 = blockIdx.x * 48;
  const u16* P = Pb + (size_t)b * NN * 1024;
  mfma_tile<2, 3>(P, P + 512, 1024,
                  VTh + (size_t)b * 480 * NN, VTl + (size_t)b * 480 * NN, NN,
                  0, NN, row0, col0, acc);
  const int lane = threadIdx.x;
  const int rb = (lane >> 4) << 2, cc = lane & 15;
  u16* oh = SRh + (size_t)b * NN * 480;
  u16* ol = SRl + (size_t)b * NN * 480;
#pragma unroll
  for (int m = 0; m < 2; ++m)
#pragma unroll
    for (int f = 0; f < 3; ++f) {
      int n = col0 + f * 16 + cc;
#pragma unroll
      for (int r = 0; r < 4; ++r) {
        float v = acc[m][f][r];
        u16 hi = f2bf(v);
        ol[(size_t)(row0 + m * 16 + rb + r) * 480 + n] = f2bf(v - bf2f(hi));
        oh[(size_t)(row0 + m * 16 + rb + r) * 480 + n] = hi;
      }
    }
}

// ---------------- output projections (live-K only, 32x48/wave) + fused delta_xyz ----------------
__global__ __launch_bounds__(64) void k_outproj(
    const u16* __restrict__ SRh, const u16* __restrict__ SRl,
    const u16* __restrict__ WOPh, const u16* __restrict__ WOPl,
    const float* __restrict__ b_so, const float* __restrict__ b_po,
    u16* PRh, u16* PRl, float* __restrict__ out_xyz) {
  f32x4 acc[2][3] = {};
  const int t = blockIdx.x;
  const int row0 = blockIdx.y * 32, col0 = t * 48;
  const int kBeg = (t < 8) ? 0 : 192, kEnd = (t < 8) ? 192 : 480;
  mfma_tile<2, 3>(SRh, SRl, 480, WOPh, WOPl, 480, kBeg, kEnd, row0, col0, acc);
  __shared__ float D[32][49];
  const int lane = threadIdx.x;
  const int rb = (lane >> 4) << 2, cc = lane & 15;
#pragma unroll
  for (int m = 0; m < 2; ++m)
#pragma unroll
    for (int f = 0; f < 3; ++f) {
      int n = col0 + f * 16 + cc;
      float bias = (n < 384) ? b_so[n] : b_po[n - 384];
#pragma unroll
      for (int r = 0; r < 4; ++r) {
        float v = acc[m][f][r] + bias;
        u16 hi = f2bf(v);
        PRh[(size_t)(row0 + m * 16 + rb + r) * 768 + n] = hi;
        PRl[(size_t)(row0 + m * 16 + rb + r) * 768 + n] = f2bf(v - bf2f(hi));
        if (t >= 8) D[m * 16 + rb + r][f * 16 + cc] = v;
      }
    }
  if (t >= 8) {
    __syncthreads();
    if (lane < 32) {
      float sx = 0.f, sy = 0.f, sz = 0.f;
#pragma unroll
      for (int p = 0; p < 16; ++p) {
        sx += D[lane][3 * p];
        sy += D[lane][3 * p + 1];
        sz += D[lane][3 * p + 2];
      }
      int token = row0 + lane;
      atomicAdd(out_xyz + (size_t)token * 3 + 0, sx * (1.0f / 128.f));
      atomicAdd(out_xyz + (size_t)token * 3 + 1, sy * (1.0f / 128.f));
      atomicAdd(out_xyz + (size_t)token * 3 + 2, sz * (1.0f / 128.f));
    }
  }
}

// ---------------- final: out = PROJ @ WFP^T + b_fp; 2 waves split K, LDS combine ----------------
__global__ __launch_bounds__(128) void k_final(
    const u16* __restrict__ PRh, const u16* __restrict__ PRl,
    const u16* __restrict__ WFPh, const u16* __restrict__ WFPl,
    const float* __restrict__ b_fp, float* __restrict__ out_res) {
  f32x4 acc[2][3] = {};
  const int row0 = blockIdx.y * 32, col0 = blockIdx.x * 48;
  const int w = threadIdx.x >> 6;
  const int kBeg = w * 384;
  mfma_tile<2, 3>(PRh, PRl, 768, WFPh, WFPl, 768, kBeg, kBeg + 384, row0, col0, acc);
  __shared__ float S[32][52];
  const int lane = threadIdx.x & 63;
  const int rb = (lane >> 4) << 2, cc = lane & 15;
  if (w == 1) {
#pragma unroll
    for (int m = 0; m < 2; ++m)
#pragma unroll
      for (int f = 0; f < 3; ++f)
#pragma unroll
        for (int r = 0; r < 4; ++r)
          S[m * 16 + rb + r][f * 16 + cc] = acc[m][f][r];
  }
  __syncthreads();
  if (w == 0) {
#pragma unroll
    for (int m = 0; m < 2; ++m)
#pragma unroll
      for (int f = 0; f < 3; ++f) {
        int n = col0 + f * 16 + cc;
#pragma unroll
        for (int r = 0; r < 4; ++r)
          out_res[(size_t)(row0 + m * 16 + rb + r) * 384 + n] =
              acc[m][f][r] + S[m * 16 + rb + r][f * 16 + cc] + b_fp[n];
      }
  }
}

extern "C" void kernel_launch(void* const* d_in, const int* in_sizes, int n_in,
                              void* d_out, int out_size, void* d_ws, size_t ws_size,
                              hipStream_t stream) {
  const float* hidden = (const float*)d_in[0];
  const float* xyz   = (const float*)d_in[1];
  const float* W_qk  = (const float*)d_in[2];
  const float* b_qk  = (const float*)d_in[3];
  const float* W_vs  = (const float*)d_in[4];
  const float* b_vs  = (const float*)d_in[5];
  const float* W_so  = (const float*)d_in[6];
  const float* b_so  = (const float*)d_in[7];
  const float* W_pqk = (const float*)d_in[8];
  const float* b_pqk = (const float*)d_in[9];
  const float* W_pv  = (const float*)d_in[10];
  const float* b_pv  = (const float*)d_in[11];
  const float* W_po  = (const float*)d_in[12];
  const float* b_po  = (const float*)d_in[13];
  const float* W_fp  = (const float*)d_in[14];
  const float* b_fp  = (const float*)d_in[15];

  float* out_res = (float*)d_out;                  // [B,N,384]
  float* out_xyz = out_res + (size_t)BB * NN * 384;

  u16* Hhi  = (u16*)d_ws;                 // 1024*384
  u16* Hlo  = Hhi  + 393216;
  u16* WINh = Hlo  + 393216;              // 1008*384
  u16* WINl = WINh + 387072;
  u16* WOPh = WINl + 387072;              // 768*480
  u16* WOPl = WOPh + 368640;
  u16* WFPh = WOPl + 368640;              // 384*768
  u16* WFPl = WFPh + 294912;
  u16* QKh  = WFPl + 294912;              // 1024*384
  u16* QKl  = QKh  + 393216;
  u16* VVh  = QKl  + 393216;              // 1024*480
  u16* VVl  = VVh  + 491520;
  u16* SRh  = VVl  + 491520;              // 1024*480
  u16* SRl  = SRh  + 491520;
  u16* PRh  = SRl  + 491520;              // 1024*768
  u16* PRl  = PRh  + 786432;
  float* QPf  = (float*)(PRl + 786432);   // 1024*144 f32
  float* ATTf = QPf + 147456;             // 2*512*512 f32 (becomes P hi/lo u16 after k_smvt)
  // VT overlays Hhi/Hlo/WINh (dead after k_input): 2*480*512 u16 x2
  u16* VTh  = Hhi;
  u16* VTl  = Hhi + 491520;

  prep_kernel<<<917, 256, 0, stream>>>(hidden, xyz, W_qk, W_vs, W_pv, W_pqk,
                                       W_so, W_po, W_fp,
                                       Hhi, Hlo, WINh, WINl, WOPh, WOPl, WFPh, WFPl,
                                       out_xyz);
  k_input<<<dim3(21, 32), 64, 0, stream>>>(Hhi, Hlo, WINh, WINl,
                                           b_qk, b_vs, b_pv, b_pqk,
                                           QKh, QKl, VVh, VVl, QPf);
  k_attn<<<dim3(136, 1, 2), 256, 0, stream>>>(QKh, QKl, QPf, ATTf);
  k_smvt<<<1504, 256, 0, stream>>>(ATTf, VVh, VVl, VTh, VTl);
  k_pv<<<dim3(10, 16, 2), 64, 0, stream>>>((const u16*)ATTf, VTh, VTl, SRh, SRl);
  k_outproj<<<dim3(16, 32), 64, 0, stream>>>(SRh, SRl, WOPh, WOPl, b_so, b_po,
                                             PRh, PRl, out_xyz);
  k_final<<<dim3(8, 32), 128, 0, stream>>>(PRh, PRl, WFPh, WFPl, b_fp, out_res);
}